// Round 1
// baseline (151.037 us; speedup 1.0000x reference)
//
#include <hip/hip_runtime.h>
#include <math.h>

#define D 256
#define B 16
#define L 8
#define N 128

static constexpr float LAMBDA_ASYNC = 0.08f;
static constexpr float LAMBDA_TAU   = 0.12f;

// ws layout (floats):
//   acc[8][B*D]   at offset 0        (8 * 4096 floats)
//   fired[8][N]   at offset 8*B*D    (8 * 128 floats)
#define WS_ACC(l)    (ws + (size_t)(l) * (B * D))
#define WS_FIRED(l)  (ws + (size_t)8 * (B * D) + (size_t)(l) * N)

// One kernel per layer. Grid: 512 blocks = node * 4 + e_quarter. Block: 256.
__global__ __launch_bounds__(256) void layer_kernel(
    const float* __restrict__ X,      // B*D  (used for l==0)
    const float* __restrict__ W,      // L*N*D*D
    const float* __restrict__ bias,   // L*N*D
    const float* __restrict__ S,      // L*N*D
    const float* __restrict__ rho,    // L*N
    const float* __restrict__ boost,  // L*N
    const int*  __restrict__ tb,      // scalar
    float* __restrict__ ws,
    int l)
{
    __shared__ float vin[B * D];          // [b][d], 16 KB
    __shared__ float colsum[D];           // 1 KB
    __shared__ float red[4 * 64 * 17];    // padded partials, ~17 KB
    __shared__ float sh_scalar[8];

    const int t  = threadIdx.x;
    const int n  = blockIdx.x >> 2;
    const int eb = blockIdx.x & 3;
    const int e0 = eb * 64;

    float* acc_cur = WS_ACC(l);

    // ---- 1) scale of V_in (= decay / cnt_prev), has_input, stage V_in in LDS
    bool has_input;
    if (l == 0) {
        has_input = true;
        for (int i = t; i < B * D; i += 256) vin[i] = X[i];
    } else {
        const float* fired_prev = WS_FIRED(l - 1);
        float f = (t < N) ? fired_prev[t] : 0.0f;
        #pragma unroll
        for (int o = 32; o > 0; o >>= 1) f += __shfl_down(f, o);
        if ((t & 63) == 0) sh_scalar[t >> 6] = f;
        __syncthreads();
        float cnt_raw = sh_scalar[0] + sh_scalar[1] + sh_scalar[2] + sh_scalar[3];
        has_input = (cnt_raw > 0.0f);
        float cnt   = fmaxf(cnt_raw, 1.0f);
        float scale = expf(-LAMBDA_ASYNC) / cnt;
        const float* acc_prev = WS_ACC(l - 1);
        for (int i = t; i < B * D; i += 256) vin[i] = acc_prev[i] * scale;
    }
    __syncthreads();

    // ---- 2) colsum[d] = sum_b V_in[b][d]
    {
        float cs = 0.0f;
        #pragma unroll
        for (int b = 0; b < B; ++b) cs += vin[b * D + t];
        colsum[t] = cs;
    }
    __syncthreads();

    // ---- 3) s_dot, firing decision (block-uniform)
    {
        float p = colsum[t] * S[(size_t)(l * N + n) * D + t];
        #pragma unroll
        for (int o = 32; o > 0; o >>= 1) p += __shfl_down(p, o);
        if ((t & 63) == 0) sh_scalar[4 + (t >> 6)] = p;
    }
    __syncthreads();
    {
        float sdot = (sh_scalar[4] + sh_scalar[5] + sh_scalar[6] + sh_scalar[7]) * (1.0f / (float)B);
        float depth = (float)(l + 1);
        float tau = 0.5f * expf(LAMBDA_TAU * (depth - (float)tb[0]));
        float ra  = rho[l * N + n] + sdot + boost[l * N + n];
        bool fired = (ra >= tau) && has_input;
        if (eb == 0 && t == 0) WS_FIRED(l)[n] = fired ? 1.0f : 0.0f;
        if (!fired) return;   // block-uniform: skip W read entirely
    }

    // ---- 4) main matmul: this block covers e in [e0, e0+64), all 256 d
    //        thread = (e_l = t&63, dq = t>>6): d range [dq*64, dq*64+64)
    const int e_l = t & 63;
    const int dq  = t >> 6;
    const float* wp = W + ((size_t)(l * N + n) * D + (size_t)(dq * 64)) * D + (e0 + e_l);

    float facc[B];
    #pragma unroll
    for (int b = 0; b < B; ++b) facc[b] = 0.0f;

    for (int d0 = 0; d0 < 64; d0 += 8) {
        float wv[8];
        #pragma unroll
        for (int u = 0; u < 8; ++u) wv[u] = wp[(size_t)(d0 + u) * D];
        #pragma unroll
        for (int u = 0; u < 8; ++u) {
            const int d = dq * 64 + d0 + u;
            #pragma unroll
            for (int b = 0; b < B; ++b)
                facc[b] = fmaf(wv[u], vin[b * D + d], facc[b]);
        }
    }

    // ---- 5) reduce 4 d-partials via LDS (pad 17 to dodge bank conflicts)
    #pragma unroll
    for (int b = 0; b < B; ++b) red[(dq * 64 + e_l) * 17 + b] = facc[b];
    __syncthreads();

    {
        const int e2 = t & 63;
        const int bg = t >> 6;
        const float bv = bias[(size_t)(l * N + n) * D + e0 + e2];
        #pragma unroll
        for (int j = 0; j < 4; ++j) {
            const int b = bg * 4 + j;
            float s = red[(0 * 64 + e2) * 17 + b]
                    + red[(1 * 64 + e2) * 17 + b]
                    + red[(2 * 64 + e2) * 17 + b]
                    + red[(3 * 64 + e2) * 17 + b];
            s += bv;
            float v = tanhf(s);
            atomicAdd(&acc_cur[b * D + e0 + e2], v);
        }
    }
}

// out[b][e] = acc7[b][e] / max(cnt7, 1)
__global__ __launch_bounds__(256) void finalize_kernel(
    const float* __restrict__ ws, float* __restrict__ out)
{
    __shared__ float sh[4];
    const int t = threadIdx.x;
    const float* fired7 = ws + (size_t)8 * (B * D) + (size_t)7 * N;
    float f = (t < N) ? fired7[t] : 0.0f;
    #pragma unroll
    for (int o = 32; o > 0; o >>= 1) f += __shfl_down(f, o);
    if ((t & 63) == 0) sh[t >> 6] = f;
    __syncthreads();
    const float cnt = fmaxf(sh[0] + sh[1] + sh[2] + sh[3], 1.0f);
    const float inv = 1.0f / cnt;
    const float* acc7 = ws + (size_t)7 * (B * D);
    for (int i = t; i < B * D; i += 256) out[i] = acc7[i] * inv;
}

extern "C" void kernel_launch(void* const* d_in, const int* in_sizes, int n_in,
                              void* d_out, int out_size, void* d_ws, size_t ws_size,
                              hipStream_t stream)
{
    const float* X     = (const float*)d_in[0];
    const float* W     = (const float*)d_in[1];
    const float* bias  = (const float*)d_in[2];
    const float* S     = (const float*)d_in[3];
    const float* rho   = (const float*)d_in[4];
    const float* boost = (const float*)d_in[5];
    const int*   tb    = (const int*)d_in[6];
    float* out = (float*)d_out;
    float* ws  = (float*)d_ws;

    // zero acc[8] + fired[8]
    const size_t ws_used = ((size_t)8 * B * D + (size_t)8 * N) * sizeof(float);
    hipMemsetAsync(d_ws, 0, ws_used, stream);

    for (int l = 0; l < L; ++l) {
        layer_kernel<<<dim3(N * 4), dim3(256), 0, stream>>>(
            X, W, bias, S, rho, boost, tb, ws, l);
    }
    finalize_kernel<<<dim3(1), dim3(256), 0, stream>>>(ws, out);
}